// Round 7
// baseline (70.381 us; speedup 1.0000x reference)
//
#include <hip/hip_runtime.h>
#include <math.h>

// CLIF spiking recurrence, [T=64, B=128, D=4096] fp32.
// R7: TWO neurons per thread, hand-interleaved chains (2-way intra-wave ILP
// to fill the ~30% VALU-idle gap R5/R6 both showed at 8 waves/SIMD).
// 262144 threads = 1024 blocks = 4 waves/SIMD; launch_bounds(256,4) so the
// register allocator does NOT serialize the two chains (R2 failure mode).
//
// NUMERICS FROZEN (R1-R6: absmax 0.0). R5 form (no LDS table):
//   - state chain in f32, single-rounded __f*_rn ops, no contraction
//   - spike test (u >= 1.0f) == fl(u-1) >= 0 (Sterbenz)
//   - spike gating via select (spike in {0,1}) -> bit-identical to multiply
//   - sigmoid: f64, fp32 result correctly rounded (rel err ~1e-11):
//     magic-add rint, y = f*ln2, deg-9 Taylor Horner, exponent-bit 2^n,
//     recip = v_rcp_f32 seed + 1 f64 Newton.
// Per-neuron op order identical to R5 -> bit-identical outputs.

#define T_STEPS 64
#define BD      (128 * 4096)     // 524288 neurons
#define HALF    (BD / 2)         // 262144 threads, neuron pair (p, p+HALF)

// Two independent correctly-rounded sigmoids, interleaved for ILP.
__device__ __forceinline__ void sigmoid2_cr(float xa, float xb,
                                            float& ra, float& rb) {
    const double SHIFT = 6755399441055744.0;      // 2^52 + 2^51
    double ta  = (double)xa * -1.4426950408889634;
    double tb  = (double)xb * -1.4426950408889634;
    double tna = ta + SHIFT;
    double tnb = tb + SHIFT;
    int    na  = __double2loint(tna);
    int    nb  = __double2loint(tnb);
    double fa  = ta - (tna - SHIFT);
    double fb  = tb - (tnb - SHIFT);
    double ya  = fa * 0.6931471805599453;         // |y| <= 0.3466
    double yb  = fb * 0.6931471805599453;
    // e^y, degree-9 Taylor (Horner); trunc err ~9.7e-12 rel
    double pa = 2.755731922398589e-6;             // 1/9!
    double pb = 2.755731922398589e-6;
    pa = fma(pa, ya, 2.480158730158730e-5);  pb = fma(pb, yb, 2.480158730158730e-5);
    pa = fma(pa, ya, 1.984126984126984e-4);  pb = fma(pb, yb, 1.984126984126984e-4);
    pa = fma(pa, ya, 1.388888888888889e-3);  pb = fma(pb, yb, 1.388888888888889e-3);
    pa = fma(pa, ya, 8.333333333333333e-3);  pb = fma(pb, yb, 8.333333333333333e-3);
    pa = fma(pa, ya, 4.166666666666666e-2);  pb = fma(pb, yb, 4.166666666666666e-2);
    pa = fma(pa, ya, 1.666666666666667e-1);  pb = fma(pb, yb, 1.666666666666667e-1);
    pa = fma(pa, ya, 0.5);                   pb = fma(pb, yb, 0.5);
    pa = fma(pa, ya, 1.0);                   pb = fma(pb, yb, 1.0);
    pa = fma(pa, ya, 1.0);                   pb = fma(pb, yb, 1.0);
    // scale by 2^n (n bounded ~[-20,20] for this data)
    double sca = __hiloint2double(0x3FF00000 + ((unsigned)na << 20), 0);
    double scb = __hiloint2double(0x3FF00000 + ((unsigned)nb << 20), 0);
    double ea  = pa * sca;
    double eb  = pb * scb;
    double da  = 1.0 + ea;
    double db  = 1.0 + eb;
    // reciprocal: f32 rcp seed (err ~6e-8) + 1 f64 Newton -> err ~4e-15
    double rra = (double)__builtin_amdgcn_rcpf((float)da);
    double rrb = (double)__builtin_amdgcn_rcpf((float)db);
    rra = rra * fma(-da, rra, 2.0);
    rrb = rrb * fma(-db, rrb, 2.0);
    ra = (float)rra;
    rb = (float)rrb;
}

// One timestep for the neuron pair, chains interleaved.
__device__ __forceinline__ void clif_step2(float& uA, float& mA, float xA,
                                           float& uB, float& mB, float xB,
                                           float& sA, float& sB) {
    uA = __fadd_rn(__fmul_rn(0.5f, uA), xA);
    uB = __fadd_rn(__fmul_rn(0.5f, uB), xB);
    bool spkA = (uA >= 1.0f);
    bool spkB = (uB >= 1.0f);
    float s1A, s1B;
    sigmoid2_cr(__fmul_rn(0.5f, uA), __fmul_rn(0.5f, uB), s1A, s1B);
    float msA = __fmul_rn(mA, s1A);
    float msB = __fmul_rn(mB, s1B);
    float mnA = spkA ? __fadd_rn(msA, 1.0f) : msA;
    float mnB = spkB ? __fadd_rn(msB, 1.0f) : msB;
    float smA, smB;
    sigmoid2_cr(mnA, mnB, smA, smB);
    uA = spkA ? __fsub_rn(uA, __fadd_rn(1.0f, smA)) : uA;
    uB = spkB ? __fsub_rn(uB, __fadd_rn(1.0f, smB)) : uB;
    mA = smA;
    mB = smB;
    sA = spkA ? 1.0f : 0.0f;
    sB = spkB ? 1.0f : 0.0f;
}

__global__ __launch_bounds__(256, 4) void clif_kernel(const float* __restrict__ x,
                                                      float* __restrict__ o) {
    int gid = blockIdx.x * blockDim.x + threadIdx.x;  // 0 .. HALF-1
    const float* xpA = x + gid;
    const float* xpB = x + gid + HALF;
    float*       opA = o + gid;
    float*       opB = o + gid + HALF;

    float uA = 0.f, mA = 0.f, uB = 0.f, mB = 0.f;
    // 2-deep prefetch ring per stream (4 loads in flight)
    float xa0 = xpA[0];
    float xb0 = xpB[0];
    float xa1 = xpA[(size_t)BD];
    float xb1 = xpB[(size_t)BD];

    #pragma unroll 1
    for (int t = 0; t < T_STEPS; t += 2) {
        int i2 = min(t + 2, T_STEPS - 1);
        int i3 = min(t + 3, T_STEPS - 1);
        float na0 = xpA[(size_t)i2 * BD];
        float nb0 = xpB[(size_t)i2 * BD];
        float na1 = xpA[(size_t)i3 * BD];
        float nb1 = xpB[(size_t)i3 * BD];

        float sA, sB;
        clif_step2(uA, mA, xa0, uB, mB, xb0, sA, sB);
        __builtin_nontemporal_store(sA, opA + (size_t)t * BD);
        __builtin_nontemporal_store(sB, opB + (size_t)t * BD);

        clif_step2(uA, mA, xa1, uB, mB, xb1, sA, sB);
        __builtin_nontemporal_store(sA, opA + (size_t)(t + 1) * BD);
        __builtin_nontemporal_store(sB, opB + (size_t)(t + 1) * BD);

        xa0 = na0; xb0 = nb0; xa1 = na1; xb1 = nb1;
    }
}

extern "C" void kernel_launch(void* const* d_in, const int* in_sizes, int n_in,
                              void* d_out, int out_size, void* d_ws, size_t ws_size,
                              hipStream_t stream) {
    const float* x = (const float*)d_in[0];
    float* out = (float*)d_out;
    dim3 block(256);
    dim3 grid(HALF / 256);  // 1024 blocks -> 4 blocks/CU -> 16 waves/CU
    clif_kernel<<<grid, block, 0, stream>>>(x, out);
}

// Round 8
// 64.500 us; speedup vs baseline: 1.0912x; 1.0912x over previous
//
#include <hip/hip_runtime.h>
#include <math.h>

// CLIF spiking recurrence, [T=64, B=128, D=4096] fp32.
// One neuron per thread; 524288 threads = 8192 waves = 8 waves/SIMD (max).
// R8: 8-deep register prefetch ring (~1700 cyc ahead) to cover HBM-miss
// latency (~900 cyc) — R5-R7 analysis: ~83% VALU-busy at speed, residual
// stall = L3-missing input loads under a 4-deep (~860 cyc) ring.
// R7 lesson: multi-neuron/thread hand-ILP gets re-serialized by the
// scheduler (VGPR=20) and halves TLP -> strictly worse. 1 neuron/thread.
//
// NUMERICS FROZEN (R1-R6: absmax 0.0). R5 form:
//   - state chain in f32, single-rounded __f*_rn ops, no contraction
//   - spike test (u >= 1.0f) == fl(u-1) >= 0 (Sterbenz)
//   - spike gating via select (spike in {0,1}) -> bit-identical to multiply
//   - sigmoid: f64, fp32 result correctly rounded (rel err ~1e-11):
//     magic-add rint, y = f*ln2, deg-9 Taylor Horner, exponent-bit 2^n,
//     recip = v_rcp_f32 seed + 1 f64 Newton.

#define T_STEPS 64
#define BD      (128 * 4096)   // 524288 neurons
#define PF      8              // prefetch depth / unroll

__device__ __forceinline__ float sigmoid_cr(float x) {
    const double SHIFT = 6755399441055744.0;     // 2^52 + 2^51
    double t  = (double)x * -1.4426950408889634; // -x * log2(e)
    double tn = t + SHIFT;                       // rint via magic add (RNE)
    int    n  = __double2loint(tn);              // low 32 bits = n (2's comp)
    double f  = t - (tn - SHIFT);                // f in [-0.5, 0.5]
    double y  = f * 0.6931471805599453;          // f * ln2, |y| <= 0.3466
    // e^y, degree-9 Taylor (Horner); trunc err ~9.7e-12 rel
    double p = 2.755731922398589e-6;             // 1/9!
    p = fma(p, y, 2.480158730158730e-5);         // 1/8!
    p = fma(p, y, 1.984126984126984e-4);         // 1/7!
    p = fma(p, y, 1.388888888888889e-3);         // 1/6!
    p = fma(p, y, 8.333333333333333e-3);         // 1/5!
    p = fma(p, y, 4.166666666666666e-2);         // 1/4!
    p = fma(p, y, 1.666666666666667e-1);         // 1/3!
    p = fma(p, y, 0.5);                          // 1/2!
    p = fma(p, y, 1.0);
    p = fma(p, y, 1.0);
    // scale by 2^n (n bounded ~[-20,20] for this data)
    double sc = __hiloint2double(0x3FF00000 + ((unsigned)n << 20), 0);
    double e  = p * sc;                          // e^{-x}
    double d  = 1.0 + e;
    // reciprocal: f32 rcp seed (err ~6e-8) + 1 f64 Newton -> err ~4e-15
    double r = (double)__builtin_amdgcn_rcpf((float)d);
    r = r * fma(-d, r, 2.0);
    return (float)r;
}

__device__ __forceinline__ float clif_step(float& u, float& m, float x) {
    // u = 0.5*u + x  (mul exact, one rounding in add)
    u = __fadd_rn(__fmul_rn(0.5f, u), x);
    bool spike = (u >= 1.0f);
    // m = m * sigmoid(0.5*u) + spike   (0.5f*u exact; +1 via select)
    float s1  = sigmoid_cr(__fmul_rn(0.5f, u));
    float ms1 = __fmul_rn(m, s1);
    float mn  = spike ? __fadd_rn(ms1, 1.0f) : ms1;
    // sm = sigmoid(m); carried as next m (in-place sigmoid_ semantics)
    float sm = sigmoid_cr(mn);
    // u = u - spike * (1 + sm)  (select form, bit-identical)
    u = spike ? __fsub_rn(u, __fadd_rn(1.0f, sm)) : u;
    m = sm;
    return spike ? 1.0f : 0.0f;
}

__global__ __launch_bounds__(256, 8) void clif_kernel(const float* __restrict__ x,
                                                      float* __restrict__ o) {
    int gid = blockIdx.x * blockDim.x + threadIdx.x;  // 0 .. BD-1
    const float* xp = x + gid;
    float*       op = o + gid;

    float u = 0.f, m = 0.f;

    // 8-deep prefetch ring (static indexing only -> stays in registers)
    float r[PF];
    #pragma unroll
    for (int k = 0; k < PF; ++k)
        r[k] = xp[(size_t)k * BD];

    #pragma unroll 1
    for (int t = 0; t < T_STEPS; t += PF) {
        float nx[PF];
        const bool more = (t + PF < T_STEPS);   // wave-uniform guard
        if (more) {
            #pragma unroll
            for (int k = 0; k < PF; ++k)
                nx[k] = xp[(size_t)(t + PF + k) * BD];
        }

        #pragma unroll
        for (int k = 0; k < PF; ++k) {
            float s = clif_step(u, m, r[k]);
            __builtin_nontemporal_store(s, op + (size_t)(t + k) * BD);
        }

        if (more) {
            #pragma unroll
            for (int k = 0; k < PF; ++k)
                r[k] = nx[k];
        }
    }
}

extern "C" void kernel_launch(void* const* d_in, const int* in_sizes, int n_in,
                              void* d_out, int out_size, void* d_ws, size_t ws_size,
                              hipStream_t stream) {
    const float* x = (const float*)d_in[0];
    float* out = (float*)d_out;
    dim3 block(256);
    dim3 grid(BD / 256);  // 2048 blocks -> 8 blocks/CU -> 32 waves/CU (max)
    clif_kernel<<<grid, block, 0, stream>>>(x, out);
}